// Round 3
// baseline (276.937 us; speedup 1.0000x reference)
//
#include <hip/hip_runtime.h>
#include <hip/hip_bf16.h>

// LoRA-factored 3x3 conv.
// x: [16,128,56,56], A: [256,16], B: [16,1152] -> out: [16,256,56,56]
// Input dtypes (fp32 vs packed bf16) detected PER TENSOR at runtime.
// Output written as fp32 (reference output dtype). No d_ws. LDS = 4KB.

#define Bn 16
#define Cc 128
#define Hh 56
#define Ww 56
#define Ll (Hh * Ww)      // 3136 = 49*64
#define Rr 16
#define Oo 256
#define KF (Cc * 9)       // 1152

__device__ __forceinline__ float bf16_bits(unsigned short u) {
    return __uint_as_float(((unsigned)u) << 16);
}

template<bool BF>
__device__ __forceinline__ float ld(const void* __restrict__ p, size_t i) {
    if constexpr (BF) return bf16_bits(((const unsigned short*)p)[i]);
    else              return ((const float*)p)[i];
}

// bf16-packed data: bits14..7 of every 32-bit word = bf16 exponent of the low
// element, always ~[96,144] for N(0,sigma) data. fp32 data: bits14..7 are
// uniform mantissa bits -> in-range with p=0.19 (~6/32). Threshold 20.
__device__ __forceinline__ bool detect_bf16(const void* __restrict__ p) {
    const unsigned* w = (const unsigned*)p;
    int c = 0;
#pragma unroll
    for (int i = 0; i < 32; ++i) {
        const unsigned e = (w[i] >> 7) & 0xFFu;
        c += (e >= 96u && e <= 144u) ? 1 : 0;
    }
    return c >= 20;
}

template<bool XB, bool AB, bool BB>
__device__ __forceinline__ void body(const void* __restrict__ x,
                                     const void* __restrict__ A,
                                     const void* __restrict__ Bm,
                                     float* __restrict__ out,
                                     float (* __restrict__ part)[64])
{
    const int tid = threadIdx.x;
    const int pix = tid & 63;        // lane within wave
    const int rg  = tid >> 6;        // wave index 0..3
    const int g   = blockIdx.x * 64 + pix;   // global pixel id, 784*64 = 50176 exact
    const int b   = g / Ll;                  // 3136 = 49*64 -> no block straddles b
    const int l   = g - b * Ll;
    const int h   = l / Ww;
    const int w   = l - h * Ww;

    // ---- stage 1: ranks r0..r0+3 for this wave ----
    const int r0 = rg * 4;
    float acc[4] = {0.f, 0.f, 0.f, 0.f};
    const size_t xbase = (size_t)b * Cc * Ll;

    for (int c = 0; c < Cc; ++c) {
        const size_t xc = xbase + (size_t)c * Ll;
        float xv[9];
#pragma unroll
        for (int dh = 0; dh < 3; ++dh) {
            const int hh = h + dh - 1;
            const bool hok = (hh >= 0) & (hh < Hh);
#pragma unroll
            for (int dw = 0; dw < 3; ++dw) {
                const int ww = w + dw - 1;
                const bool ok = hok & (ww >= 0) & (ww < Ww);
                xv[dh * 3 + dw] = ok ? ld<XB>(x, xc + (size_t)(hh * Ww + ww)) : 0.0f;
            }
        }
#pragma unroll
        for (int j = 0; j < 4; ++j) {
            const size_t bo = (size_t)(r0 + j) * KF + (size_t)c * 9;  // wave-uniform
            float s = acc[j];
#pragma unroll
            for (int i = 0; i < 9; ++i) s += ld<BB>(Bm, bo + i) * xv[i];
            acc[j] = s;
        }
    }

    // ---- exchange: part[r][pix], stride-1 across lanes -> conflict-free ----
#pragma unroll
    for (int j = 0; j < 4; ++j) part[r0 + j][pix] = acc[j];
    __syncthreads();   // all 256 threads reach this (no early returns)

    float tv[Rr];
#pragma unroll
    for (int r = 0; r < Rr; ++r) tv[r] = part[r][pix];

    // ---- stage 2: wave rg emits output channels rg*64 .. rg*64+63 ----
    const size_t obase = (size_t)b * Oo * Ll + (size_t)l;
#pragma unroll 4
    for (int oo = 0; oo < 64; ++oo) {
        const int o = rg * 64 + oo;
        float s = 0.f;
#pragma unroll
        for (int r = 0; r < Rr; ++r) s += ld<AB>(A, (size_t)o * Rr + r) * tv[r];
        out[obase + (size_t)o * Ll] = s;   // fp32 store, coalesced across lanes
    }
}

__global__ __launch_bounds__(256) void fused_kernel(
    const void* __restrict__ x,
    const void* __restrict__ A,
    const void* __restrict__ Bm,
    float* __restrict__ out)
{
    __shared__ float part[Rr][64];   // 4 KB

    // Uniform across the block: every thread computes identical detector bits.
    const bool xb = detect_bf16(x);
    const bool ab = detect_bf16(A);
    const bool bb = detect_bf16(Bm);

    if (xb) {
        if (ab) { if (bb) body<true , true , true >(x, A, Bm, out, part);
                  else    body<true , true , false>(x, A, Bm, out, part); }
        else    { if (bb) body<true , false, true >(x, A, Bm, out, part);
                  else    body<true , false, false>(x, A, Bm, out, part); }
    } else {
        if (ab) { if (bb) body<false, true , true >(x, A, Bm, out, part);
                  else    body<false, true , false>(x, A, Bm, out, part); }
        else    { if (bb) body<false, false, true >(x, A, Bm, out, part);
                  else    body<false, false, false>(x, A, Bm, out, part); }
    }
}

extern "C" void kernel_launch(void* const* d_in, const int* in_sizes, int n_in,
                              void* d_out, int out_size, void* d_ws, size_t ws_size,
                              hipStream_t stream) {
    // Identify inputs BY SIZE (robust to ordering surprises).
    const void* x  = d_in[0];
    const void* A  = d_in[1];
    const void* Bm = d_in[2];
    for (int i = 0; i < n_in && i < 3; ++i) {
        const int s = in_sizes[i];
        if      (s == Bn * Cc * Ll) x  = d_in[i];
        else if (s == Oo * Rr)      A  = d_in[i];
        else if (s == Rr * KF)      Bm = d_in[i];
    }
    float* out = (float*)d_out;

    fused_kernel<<<dim3((Bn * Ll) / 64), 256, 0, stream>>>(x, A, Bm, out);
}